// Round 11
// baseline (371.185 us; speedup 1.0000x reference)
//
#include <hip/hip_runtime.h>

// BatchTopK: relu(x), keep global top (k*1024) of 1024*24576 fp32, zero rest.
// Exact radix-select on positive-fp32 bit patterns + index-ordered tie-break.
//
// R11: (1) out=0 via hipMemsetAsync (the harness's own fill path measured at
// 7TB/s; our in-kernel stores never beat 2.4TB/s). (2) k_read is PURE READ
// (R5's fastest hot loop, no stores). (3) Tail collapsed: scan fused into
// k_read's last block, select fused into k_filter's last block (done-counter
// + threadfence last-block pattern); tail was ~58us over 7 launches.

#define N_ELEM   25165824            // 1024 * 24576
#define NV       (N_ELEM / 4)        // float4 count = 6291456 = 2048*256*12
#define HIST_SIZE 4096               // top-12-bit buckets
#define HREP     8                   // hist replicas
#define SREP     8                   // sample blocks / private replicas
#define NS       (NV / 64)           // sampled float4 count (1/64)
#define LCAP     1024                // per-block LDS candidate buffer
#define LCAP2    1024
#define TIE_CAP  4096
#define CAND2_CAP 262144
#define CAND_CAP  8388608

typedef float f32x4 __attribute__((ext_vector_type(4)));

// ws layout (uint32 words):
#define H_OFF     0                            // 8 x 4096 main hist (bits >= F)
#define H2_OFF    (H_OFF + HREP * HIST_SIZE)   // 32768: 8 x 4096 level-2 hist
#define HS_OFF    (H2_OFF + HREP * HIST_SIZE)  // 65536: 8 x 4096 sample replicas
#define META_OFF  (HS_OFF + SREP * HIST_SIZE)  // 98304: 32 words
#define CAND2_OFF (META_OFF + 32)              // 98336 (even -> uint2 ok)
#define CAND_OFF  (CAND2_OFF + 2 * CAND2_CAP)  // 622624 (even)
// meta: [0]=cand cnt [1]=b12 [2]=c_above [3]=fail [4]=F [5]=keepall
//       [7]=cand2 cnt [8]=cand snapshot [9]=done_read [10]=done_fb [11]=done_fs

// K1 (8 blocks): zero H+H2+meta; 1/64 sample -> private replica (plain stores).
__global__ void k_prep(const float4* __restrict__ x, unsigned* __restrict__ ws) {
    __shared__ unsigned lh[HIST_SIZE];
    for (int i = threadIdx.x; i < HIST_SIZE; i += 256) lh[i] = 0u;
    int gid = blockIdx.x * 256 + threadIdx.x;
    for (int i = gid; i < HS_OFF; i += SREP * 256) ws[i] = 0u;   // zero H + H2
    if (gid < 32) ws[META_OFF + gid] = 0u;                        // meta + done ctrs
    __syncthreads();
    for (int s = gid; s < NS; s += SREP * 256) {
        int c = s >> 6, l = s & 63;          // first 64 f4 of each 4096-f4 chunk
        float4 v = x[c * 4096 + l];
        if (v.x > 0.0f) atomicAdd(&lh[__float_as_uint(v.x) >> 20], 1u);
        if (v.y > 0.0f) atomicAdd(&lh[__float_as_uint(v.y) >> 20], 1u);
        if (v.z > 0.0f) atomicAdd(&lh[__float_as_uint(v.z) >> 20], 1u);
        if (v.w > 0.0f) atomicAdd(&lh[__float_as_uint(v.w) >> 20], 1u);
    }
    __syncthreads();
    unsigned* hs = ws + HS_OFF + blockIdx.x * HIST_SIZE;
    for (int i = threadIdx.x; i < HIST_SIZE; i += 256) hs[i] = lh[i];
}

// K2 (1 block x 1024): F = highest bucket with sampled suffix >= nk/32
// (expected full count(>=F) ~ 2*nk; exact fallback guards the tail).
__global__ void k_pick(unsigned* __restrict__ ws, const int* __restrict__ kptr) {
    __shared__ unsigned h[HIST_SIZE];
    __shared__ unsigned ps[1024];
    __shared__ unsigned F_sh;
    int t = threadIdx.x;
    if (t == 0) F_sh = 1u;
    unsigned nk = (unsigned)(*kptr) * 1024u;
    unsigned thr = nk / 32u; if (thr < 1u) thr = 1u;
    for (int i = t; i < HIST_SIZE; i += 1024) {
        unsigned s = 0u;
        #pragma unroll
        for (int r = 0; r < SREP; ++r) s += ws[HS_OFF + r * HIST_SIZE + i];
        h[i] = s;
    }
    __syncthreads();
    unsigned p = h[t*4] + h[t*4+1] + h[t*4+2] + h[t*4+3];
    ps[t] = p;
    __syncthreads();
    for (int st = 1; st < 1024; st <<= 1) {
        unsigned v = (t + st < 1024) ? ps[t + st] : 0u;
        __syncthreads();
        ps[t] += v;
        __syncthreads();
    }
    unsigned S = (t < 1023) ? ps[t + 1] : 0u;
    for (int j = 3; j >= 0; --j) {
        int b = t * 4 + j;
        unsigned Sb = S + h[b];
        if (Sb >= thr && S < thr) F_sh = ((unsigned)b) << 20;
        S = Sb;
    }
    __syncthreads();
    if (t == 0) ws[META_OFF + 4] = F_sh;
}

__device__ __forceinline__ void push_cand(unsigned b, unsigned idx,
                                          unsigned* lcnt, uint2* lc,
                                          unsigned* gcnt, uint2* cand, unsigned cap,
                                          unsigned* gh) {
    unsigned p = atomicAdd(lcnt, 1u);
    if (p < LCAP) lc[p] = make_uint2(b, idx);
    else {                                    // spill (~never): keep hist exact
        unsigned q = atomicAdd(gcnt, 1u);
        if (q < cap) { cand[q] = make_uint2(b, idx); atomicAdd(&gh[b >> 20], 1u); }
    }
}

// K3 (2048 x 256): PURE READ stream + compact (R5 hot loop, no stores) +
// packed-u16 hist epilogue + last-block fused suffix-scan.
__global__ __launch_bounds__(256) void k_read(const float4* __restrict__ x,
                                              unsigned* __restrict__ ws,
                                              uint2* __restrict__ cand, unsigned cap,
                                              const int* __restrict__ kptr) {
    __shared__ unsigned pool[4096];          // [0,2048)=lc(uint2*1024) [2048,4096)=lhp; scan reuses as h[4096]
    __shared__ unsigned ps[256];
    __shared__ unsigned lcnt, gbase, islast;
    uint2* lc = reinterpret_cast<uint2*>(pool);
    unsigned* lhp = pool + 2048;
    if (threadIdx.x == 0) lcnt = 0u;
    for (int i = threadIdx.x; i < 2048; i += 256) lhp[i] = 0u;
    __syncthreads();
    unsigned* meta = ws + META_OFF;
    const unsigned F = meta[4];
    unsigned* gcnt = &meta[0];
    unsigned* gh = ws + H_OFF + (blockIdx.x & (HREP - 1)) * HIST_SIZE;
    int tid = blockIdx.x * 256 + threadIdx.x;
    const int stride = 2048 * 256;
    #pragma unroll
    for (int j = 0; j < 12; j += 4) {
        float4 v0 = x[tid + (j + 0) * stride];
        float4 v1 = x[tid + (j + 1) * stride];
        float4 v2 = x[tid + (j + 2) * stride];
        float4 v3 = x[tid + (j + 3) * stride];
        #pragma unroll
        for (int q = 0; q < 4; ++q) {
            float4 v = (q == 0) ? v0 : (q == 1) ? v1 : (q == 2) ? v2 : v3;
            unsigned base = (unsigned)(tid + (j + q) * stride) * 4u;
            unsigned b;
            b = __float_as_uint(fmaxf(v.x, 0.f)); if (b >= F) push_cand(b, base + 0u, &lcnt, lc, gcnt, cand, cap, gh);
            b = __float_as_uint(fmaxf(v.y, 0.f)); if (b >= F) push_cand(b, base + 1u, &lcnt, lc, gcnt, cand, cap, gh);
            b = __float_as_uint(fmaxf(v.z, 0.f)); if (b >= F) push_cand(b, base + 2u, &lcnt, lc, gcnt, cand, cap, gh);
            b = __float_as_uint(fmaxf(v.w, 0.f)); if (b >= F) push_cand(b, base + 3u, &lcnt, lc, gcnt, cand, cap, gh);
        }
    }
    __syncthreads();
    unsigned n = lcnt < LCAP ? lcnt : LCAP;
    for (unsigned e = threadIdx.x; e < n; e += 256) {
        unsigned b12 = lc[e].x >> 20;
        atomicAdd(&lhp[b12 >> 1], 1u << ((b12 & 1u) * 16u));
    }
    __syncthreads();
    if (threadIdx.x == 0 && n) gbase = atomicAdd(gcnt, n);
    __syncthreads();
    for (unsigned e = threadIdx.x; e < n; e += 256) {
        unsigned q = gbase + e;
        if (q < cap) cand[q] = lc[e];
    }
    for (int i = threadIdx.x; i < 2048; i += 256) {
        unsigned w = lhp[i];
        if (w & 0xFFFFu) atomicAdd(&gh[i * 2],     w & 0xFFFFu);
        if (w >> 16)     atomicAdd(&gh[i * 2 + 1], w >> 16);
    }
    // ---- fused scan in the last-finished block ----
    __threadfence();
    __syncthreads();
    if (threadIdx.x == 0) {
        unsigned d = atomicAdd(&meta[9], 1u);
        islast = (d == 2047u) ? 1u : 0u;
    }
    __syncthreads();
    if (!islast) return;
    __threadfence();
    unsigned* h = pool;                       // reuse pool as h[4096]
    int t = threadIdx.x;
    for (int i = t; i < HIST_SIZE; i += 256) {
        unsigned s = 0u;
        #pragma unroll
        for (int r = 0; r < HREP; ++r) s += ws[H_OFF + r * HIST_SIZE + i];
        h[i] = s;
    }
    __syncthreads();
    unsigned nk = (unsigned)(*kptr) * 1024u;
    unsigned chunk = 0u;
    #pragma unroll
    for (int rj = 0; rj < 16; ++rj) chunk += h[t * 16 + rj];
    ps[t] = chunk;
    __syncthreads();
    for (int st = 1; st < 256; st <<= 1) {
        unsigned v = (t + st < 256) ? ps[t + st] : 0u;
        __syncthreads();
        ps[t] += v;
        __syncthreads();
    }
    unsigned total = ps[0];
    if (total < nk) {
        if (t == 0) { meta[3] = 1u; meta[8] = atomicAdd(&meta[0], 0u); }
        return;
    }
    unsigned S = (t < 255) ? ps[t + 1] : 0u;
    for (int j = 15; j >= 0; --j) {
        int b = t * 16 + j;
        unsigned Sb = S + h[b];
        if (Sb >= nk && S < nk) { meta[1] = (unsigned)b; meta[2] = S; }
        S = Sb;
    }
}

// K4 (2048 x 256, guarded on fail): complement pass (0 < bits < F) appends
// candidates + hist; last block rescans full hist -> keepall | updated b12.
__global__ __launch_bounds__(256) void k_fb(const float4* __restrict__ x,
                                            unsigned* __restrict__ ws,
                                            uint2* __restrict__ cand, unsigned cap,
                                            const int* __restrict__ kptr) {
    unsigned* meta = ws + META_OFF;
    if (meta[3] == 0u) return;
    __shared__ unsigned pool[4096];
    __shared__ unsigned ps[256];
    __shared__ unsigned lcnt, gbase, islast;
    uint2* lc = reinterpret_cast<uint2*>(pool);
    unsigned* lhp = pool + 2048;
    if (threadIdx.x == 0) lcnt = 0u;
    for (int i = threadIdx.x; i < 2048; i += 256) lhp[i] = 0u;
    __syncthreads();
    const unsigned F = meta[4];
    unsigned* gcnt = &meta[0];
    unsigned* gh = ws + H_OFF + (blockIdx.x & (HREP - 1)) * HIST_SIZE;
    int stride = gridDim.x * blockDim.x;
    for (int i = blockIdx.x * blockDim.x + threadIdx.x; i < NV; i += stride) {
        float4 v = x[i];
        unsigned base = (unsigned)i * 4u;
        #pragma unroll
        for (int c = 0; c < 4; ++c) {
            float a = (c == 0) ? v.x : (c == 1) ? v.y : (c == 2) ? v.z : v.w;
            unsigned b = __float_as_uint(fmaxf(a, 0.f));
            if (b >= 1u && b < F) push_cand(b, base + (unsigned)c, &lcnt, lc, gcnt, cand, cap, gh);
        }
    }
    __syncthreads();
    unsigned n = lcnt < LCAP ? lcnt : LCAP;
    for (unsigned e = threadIdx.x; e < n; e += 256) {
        unsigned b12 = lc[e].x >> 20;
        atomicAdd(&lhp[b12 >> 1], 1u << ((b12 & 1u) * 16u));
    }
    __syncthreads();
    if (threadIdx.x == 0 && n) gbase = atomicAdd(gcnt, n);
    __syncthreads();
    for (unsigned e = threadIdx.x; e < n; e += 256) {
        unsigned q = gbase + e;
        if (q < cap) cand[q] = lc[e];
    }
    for (int i = threadIdx.x; i < 2048; i += 256) {
        unsigned w = lhp[i];
        if (w & 0xFFFFu) atomicAdd(&gh[i * 2],     w & 0xFFFFu);
        if (w >> 16)     atomicAdd(&gh[i * 2 + 1], w >> 16);
    }
    __threadfence();
    __syncthreads();
    if (threadIdx.x == 0) {
        unsigned d = atomicAdd(&meta[10], 1u);
        islast = (d == gridDim.x - 1u) ? 1u : 0u;
    }
    __syncthreads();
    if (!islast) return;
    __threadfence();
    unsigned* h = pool;
    int t = threadIdx.x;
    for (int i = t; i < HIST_SIZE; i += 256) {
        unsigned s = 0u;
        #pragma unroll
        for (int r = 0; r < HREP; ++r) s += ws[H_OFF + r * HIST_SIZE + i];
        h[i] = s;
    }
    __syncthreads();
    unsigned nk = (unsigned)(*kptr) * 1024u;
    unsigned chunk = 0u;
    #pragma unroll
    for (int rj = 0; rj < 16; ++rj) chunk += h[t * 16 + rj];
    ps[t] = chunk;
    __syncthreads();
    for (int st = 1; st < 256; st <<= 1) {
        unsigned v = (t + st < 256) ? ps[t + st] : 0u;
        __syncthreads();
        ps[t] += v;
        __syncthreads();
    }
    unsigned total = ps[0];
    if (total < nk) {
        if (t == 0) meta[5] = 1u;            // keep all positives
        return;
    }
    unsigned S = (t < 255) ? ps[t + 1] : 0u;
    for (int j = 15; j >= 0; --j) {
        int b = t * 16 + j;
        unsigned Sb = S + h[b];
        if (Sb >= nk && S < nk) { meta[1] = (unsigned)b; meta[2] = S; }
        S = Sb;
    }
}

// K5 (256 x 256): filter (scatter bucket>b12 keepers; compact ==b12 -> cand2 +
// level-2 hist) + last-block fused select (exact tau, scatter + tie-break).
__global__ __launch_bounds__(256) void k_fs(unsigned* __restrict__ ws,
                                            const uint2* __restrict__ cand,
                                            uint2* __restrict__ cand2,
                                            float* __restrict__ out, unsigned cap,
                                            const int* __restrict__ kptr) {
    __shared__ unsigned pool[8704];  // filter: lc2[1024] (2048w). select: h[4096], ties[4096], h3[256], ps[256]
    __shared__ unsigned lcnt, gbase, islast, tie_cnt;
    __shared__ unsigned s2_sh, ca2_sh, t3_sh, ca3_sh;
    unsigned* meta = ws + META_OFF;
    unsigned keepall = meta[5];
    unsigned ncand = meta[0]; if (ncand > cap) ncand = cap;
    unsigned stride = gridDim.x * blockDim.x;
    if (keepall) {
        for (unsigned i = blockIdx.x * blockDim.x + threadIdx.x; i < ncand; i += stride) {
            uint2 c = cand[i];
            out[c.y] = __uint_as_float(c.x);
        }
        return;
    }
    uint2* lc2 = reinterpret_cast<uint2*>(pool);
    if (threadIdx.x == 0) { lcnt = 0u; tie_cnt = 0u; }
    __syncthreads();
    unsigned b12 = meta[1];
    unsigned* h2 = ws + H2_OFF + (blockIdx.x & (HREP - 1)) * HIST_SIZE;
    unsigned* cnt2 = &meta[7];
    for (unsigned i = blockIdx.x * blockDim.x + threadIdx.x; i < ncand; i += stride) {
        uint2 c = cand[i];
        unsigned bk = c.x >> 20;
        if (bk > b12) {
            out[c.y] = __uint_as_float(c.x);       // definite keeper
        } else if (bk == b12) {
            atomicAdd(&h2[(c.x >> 8) & 0xFFFu], 1u);
            unsigned p = atomicAdd(&lcnt, 1u);
            if (p < LCAP2) lc2[p] = c;
            else { unsigned q = atomicAdd(cnt2, 1u); if (q < CAND2_CAP) cand2[q] = c; }
        }
    }
    __syncthreads();
    unsigned n = lcnt < LCAP2 ? lcnt : LCAP2;
    if (threadIdx.x == 0 && n) gbase = atomicAdd(cnt2, n);
    __syncthreads();
    for (unsigned e = threadIdx.x; e < n; e += 256) {
        unsigned q = gbase + e;
        if (q < CAND2_CAP) cand2[q] = lc2[e];
    }
    __threadfence();
    __syncthreads();
    if (threadIdx.x == 0) {
        unsigned d = atomicAdd(&meta[11], 1u);
        islast = (d == gridDim.x - 1u) ? 1u : 0u;
    }
    __syncthreads();
    if (!islast) return;
    __threadfence();
    // ---- select (256 threads) ----
    unsigned* h  = pool;
    int* ties    = reinterpret_cast<int*>(pool + 4096);
    unsigned* h3 = pool + 8192;
    unsigned* ps = pool + 8448;
    int t = threadIdx.x;
    unsigned nk = (unsigned)(*kptr) * 1024u;
    unsigned m = nk - meta[2];                     // rank within bucket b12, >=1
    unsigned n2 = atomicAdd(&meta[7], 0u); if (n2 > CAND2_CAP) n2 = CAND2_CAP;
    for (int i = t; i < HIST_SIZE; i += 256) {
        unsigned s = 0u;
        #pragma unroll
        for (int r = 0; r < HREP; ++r) s += ws[H2_OFF + r * HIST_SIZE + i];
        h[i] = s;
    }
    h3[t] = 0u;
    __syncthreads();
    unsigned chunk = 0u;
    #pragma unroll
    for (int rj = 0; rj < 16; ++rj) chunk += h[t * 16 + rj];
    ps[t] = chunk;
    __syncthreads();
    for (int st = 1; st < 256; st <<= 1) {
        unsigned v = (t + st < 256) ? ps[t + st] : 0u;
        __syncthreads();
        ps[t] += v;
        __syncthreads();
    }
    {
        unsigned S = (t < 255) ? ps[t + 1] : 0u;
        for (int j = 15; j >= 0; --j) {
            int b = t * 16 + j;
            unsigned Sb = S + h[b];
            if (Sb >= m && S < m) { s2_sh = (unsigned)b; ca2_sh = S; }
            S = Sb;
        }
    }
    __syncthreads();
    unsigned s2 = s2_sh;
    unsigned m2 = m - ca2_sh;                      // rank within sub-bucket, >=1
    for (unsigned i = t; i < n2; i += 256) {
        uint2 c = cand2[i];
        if (((c.x >> 8) & 0xFFFu) == s2) atomicAdd(&h3[c.x & 0xFFu], 1u);
    }
    __syncthreads();
    ps[t] = h3[t];
    __syncthreads();
    for (int st = 1; st < 256; st <<= 1) {
        unsigned v = (t + st < 256) ? ps[t + st] : 0u;
        __syncthreads();
        ps[t] += v;
        __syncthreads();
    }
    {
        unsigned S3 = (t < 255) ? ps[t + 1] : 0u;
        unsigned Sb = S3 + h3[t];
        if (Sb >= m2 && S3 < m2) { t3_sh = (unsigned)t; ca3_sh = S3; }
    }
    __syncthreads();
    unsigned tau = (b12 << 20) | (s2 << 8) | t3_sh;
    unsigned r = m2 - ca3_sh;                      // exact-tie keepers
    for (unsigned i = t; i < n2; i += 256) {
        uint2 c = cand2[i];
        if (c.x > tau) {
            out[c.y] = __uint_as_float(c.x);       // in-bucket definite keeper
        } else if (c.x == tau) {
            unsigned q = atomicAdd(&tie_cnt, 1u);
            if (q < TIE_CAP) ties[q] = (int)c.y;
        }
    }
    __syncthreads();
    unsigned tc = tie_cnt; if (tc > TIE_CAP) tc = TIE_CAP;
    float tv = __uint_as_float(tau);
    for (unsigned e = t; e < tc; e += 256) {
        int my = ties[e];
        unsigned rank = 0u;
        for (unsigned j = 0; j < tc; ++j) rank += (ties[j] < my) ? 1u : 0u;
        if (rank < r) out[my] = tv;                // keep r lowest-index ties
    }
}

extern "C" void kernel_launch(void* const* d_in, const int* in_sizes, int n_in,
                              void* d_out, int out_size, void* d_ws, size_t ws_size,
                              hipStream_t stream) {
    const float4* x = (const float4*)d_in[0];
    const int* kptr = (const int*)d_in[1];
    float* out = (float*)d_out;
    unsigned* ws32 = (unsigned*)d_ws;
    uint2* cand2 = (uint2*)(ws32 + CAND2_OFF);
    uint2* cand  = (uint2*)(ws32 + CAND_OFF);

    unsigned cap = CAND_CAP;
    size_t hdr = (size_t)CAND_OFF * 4;
    if (ws_size < hdr + (size_t)CAND_CAP * 8) {
        cap = (ws_size > hdr) ? (unsigned)((ws_size - hdr) / 8) : 0u;
    }

    hipMemsetAsync(d_out, 0, (size_t)out_size * sizeof(float), stream);  // 7TB/s fill path
    k_prep<<<SREP, 256, 0, stream>>>(x, ws32);
    k_pick<<<1, 1024, 0, stream>>>(ws32, kptr);
    k_read<<<2048, 256, 0, stream>>>(x, ws32, cand, cap, kptr);
    k_fb<<<2048, 256, 0, stream>>>(x, ws32, cand, cap, kptr);   // no-op unless fail
    k_fs<<<256, 256, 0, stream>>>(ws32, cand, cand2, out, cap, kptr);
}

// Round 12
// 141.482 us; speedup vs baseline: 2.6236x; 2.6236x over previous
//
#include <hip/hip_runtime.h>

// BatchTopK: relu(x), keep global top (k*1024) of 1024*24576 fp32, zero rest.
// Exact radix-select on positive-fp32 bit patterns + index-ordered tie-break.
//
// R12: R11's last-block fusion REMOVED — per-block __threadfence() on gfx950
// is an L2 writeback (XCD non-coherence): 2048 of them serialized k_read to
// 280us. Keep the two wins: hipMemsetAsync zero-fill (7TB/s path) and pure-
// read k_read. Tail = separate small kernels (launch ~3-5us each << fences).

#define N_ELEM   25165824            // 1024 * 24576
#define NV       (N_ELEM / 4)        // float4 count = 6291456 = 2048*256*12
#define HIST_SIZE 4096               // top-12-bit buckets
#define HREP     8                   // hist replicas
#define SREP     8                   // sample blocks / private replicas
#define NS       (NV / 64)           // sampled float4 count (1/64)
#define LCAP     1024                // per-block LDS candidate buffer
#define LCAP2    1024
#define TIE_CAP  4096
#define CAND2_CAP 262144
#define CAND_CAP  8388608

// ws layout (uint32 words):
#define H_OFF     0                            // 8 x 4096 main hist (bits >= F)
#define H2_OFF    (H_OFF + HREP * HIST_SIZE)   // 32768: 8 x 4096 level-2 hist
#define HS_OFF    (H2_OFF + HREP * HIST_SIZE)  // 65536: 8 x 4096 sample replicas
#define META_OFF  (HS_OFF + SREP * HIST_SIZE)  // 98304: 32 words
#define CAND2_OFF (META_OFF + 32)              // 98336 (even -> uint2 ok)
#define CAND_OFF  (CAND2_OFF + 2 * CAND2_CAP)  // 622624 (even)
// meta: [0]=cand cnt [1]=b12 [2]=c_above [3]=fail [4]=F [5]=keepall
//       [7]=cand2 cnt [8]=cand snapshot

// K1 (8 blocks): zero H+H2+meta; 1/64 sample -> private replica (plain stores).
__global__ void k_prep(const float4* __restrict__ x, unsigned* __restrict__ ws) {
    __shared__ unsigned lh[HIST_SIZE];
    for (int i = threadIdx.x; i < HIST_SIZE; i += 256) lh[i] = 0u;
    int gid = blockIdx.x * 256 + threadIdx.x;
    for (int i = gid; i < HS_OFF; i += SREP * 256) ws[i] = 0u;   // zero H + H2
    if (gid < 32) ws[META_OFF + gid] = 0u;
    __syncthreads();
    for (int s = gid; s < NS; s += SREP * 256) {
        int c = s >> 6, l = s & 63;          // first 64 f4 of each 4096-f4 chunk
        float4 v = x[c * 4096 + l];
        if (v.x > 0.0f) atomicAdd(&lh[__float_as_uint(v.x) >> 20], 1u);
        if (v.y > 0.0f) atomicAdd(&lh[__float_as_uint(v.y) >> 20], 1u);
        if (v.z > 0.0f) atomicAdd(&lh[__float_as_uint(v.z) >> 20], 1u);
        if (v.w > 0.0f) atomicAdd(&lh[__float_as_uint(v.w) >> 20], 1u);
    }
    __syncthreads();
    unsigned* hs = ws + HS_OFF + blockIdx.x * HIST_SIZE;
    for (int i = threadIdx.x; i < HIST_SIZE; i += 256) hs[i] = lh[i];
}

// K2 (1 block x 1024): F = highest bucket with sampled suffix >= nk/32
// (expected full count(>=F) ~ 2*nk; exact fallback guards the tail).
__global__ void k_pick(unsigned* __restrict__ ws, const int* __restrict__ kptr) {
    __shared__ unsigned h[HIST_SIZE];
    __shared__ unsigned ps[1024];
    __shared__ unsigned F_sh;
    int t = threadIdx.x;
    if (t == 0) F_sh = 1u;
    unsigned nk = (unsigned)(*kptr) * 1024u;
    unsigned thr = nk / 32u; if (thr < 1u) thr = 1u;
    for (int i = t; i < HIST_SIZE; i += 1024) {
        unsigned s = 0u;
        #pragma unroll
        for (int r = 0; r < SREP; ++r) s += ws[HS_OFF + r * HIST_SIZE + i];
        h[i] = s;
    }
    __syncthreads();
    unsigned p = h[t*4] + h[t*4+1] + h[t*4+2] + h[t*4+3];
    ps[t] = p;
    __syncthreads();
    for (int st = 1; st < 1024; st <<= 1) {
        unsigned v = (t + st < 1024) ? ps[t + st] : 0u;
        __syncthreads();
        ps[t] += v;
        __syncthreads();
    }
    unsigned S = (t < 1023) ? ps[t + 1] : 0u;
    for (int j = 3; j >= 0; --j) {
        int b = t * 4 + j;
        unsigned Sb = S + h[b];
        if (Sb >= thr && S < thr) F_sh = ((unsigned)b) << 20;
        S = Sb;
    }
    __syncthreads();
    if (t == 0) ws[META_OFF + 4] = F_sh;
}

__device__ __forceinline__ void push_cand(unsigned b, unsigned idx,
                                          unsigned* lcnt, uint2* lc,
                                          unsigned* gcnt, uint2* cand, unsigned cap,
                                          unsigned* gh) {
    unsigned p = atomicAdd(lcnt, 1u);
    if (p < LCAP) lc[p] = make_uint2(b, idx);
    else {                                    // spill (~never): keep hist exact
        unsigned q = atomicAdd(gcnt, 1u);
        if (q < cap) { cand[q] = make_uint2(b, idx); atomicAdd(&gh[b >> 20], 1u); }
    }
}

// K3 (2048 x 256): PURE READ stream + candidate compaction + packed-u16
// block-local histogram epilogue. No stores in hot loop, no fences.
__global__ __launch_bounds__(256) void k_read(const float4* __restrict__ x,
                                              unsigned* __restrict__ ws,
                                              uint2* __restrict__ cand, unsigned cap) {
    __shared__ uint2 lc[LCAP];               // 8 KB
    __shared__ unsigned lhp[HIST_SIZE / 2];  // 8 KB packed u16 pairs
    __shared__ unsigned lcnt, gbase;
    if (threadIdx.x == 0) lcnt = 0u;
    for (int i = threadIdx.x; i < HIST_SIZE / 2; i += 256) lhp[i] = 0u;
    __syncthreads();
    unsigned* meta = ws + META_OFF;
    const unsigned F = meta[4];
    unsigned* gcnt = &meta[0];
    unsigned* gh = ws + H_OFF + (blockIdx.x & (HREP - 1)) * HIST_SIZE;
    int tid = blockIdx.x * 256 + threadIdx.x;
    const int stride = 2048 * 256;
    #pragma unroll
    for (int j = 0; j < 12; j += 4) {
        float4 v0 = x[tid + (j + 0) * stride];
        float4 v1 = x[tid + (j + 1) * stride];
        float4 v2 = x[tid + (j + 2) * stride];
        float4 v3 = x[tid + (j + 3) * stride];
        #pragma unroll
        for (int q = 0; q < 4; ++q) {
            float4 v = (q == 0) ? v0 : (q == 1) ? v1 : (q == 2) ? v2 : v3;
            unsigned base = (unsigned)(tid + (j + q) * stride) * 4u;
            unsigned b;
            b = __float_as_uint(fmaxf(v.x, 0.f)); if (b >= F) push_cand(b, base + 0u, &lcnt, lc, gcnt, cand, cap, gh);
            b = __float_as_uint(fmaxf(v.y, 0.f)); if (b >= F) push_cand(b, base + 1u, &lcnt, lc, gcnt, cand, cap, gh);
            b = __float_as_uint(fmaxf(v.z, 0.f)); if (b >= F) push_cand(b, base + 2u, &lcnt, lc, gcnt, cand, cap, gh);
            b = __float_as_uint(fmaxf(v.w, 0.f)); if (b >= F) push_cand(b, base + 3u, &lcnt, lc, gcnt, cand, cap, gh);
        }
    }
    __syncthreads();
    unsigned n = lcnt < LCAP ? lcnt : LCAP;
    for (unsigned e = threadIdx.x; e < n; e += 256) {
        unsigned b12 = lc[e].x >> 20;
        atomicAdd(&lhp[b12 >> 1], 1u << ((b12 & 1u) * 16u));
    }
    __syncthreads();
    if (threadIdx.x == 0 && n) gbase = atomicAdd(gcnt, n);
    __syncthreads();
    for (unsigned e = threadIdx.x; e < n; e += 256) {
        unsigned q = gbase + e;
        if (q < cap) cand[q] = lc[e];
    }
    for (int i = threadIdx.x; i < HIST_SIZE / 2; i += 256) {
        unsigned w = lhp[i];
        if (w & 0xFFFFu) atomicAdd(&gh[i * 2],     w & 0xFFFFu);
        if (w >> 16)     atomicAdd(&gh[i * 2 + 1], w >> 16);
    }
}

// K4 (2048, guarded on fail): complement pass (0 < bits < F) appends
// candidates + hist counts, restoring full-histogram exactness.
__global__ void k_fb(const float4* __restrict__ x, unsigned* __restrict__ ws,
                     uint2* __restrict__ cand, unsigned cap) {
    unsigned* meta = ws + META_OFF;
    if (meta[3] == 0u) return;
    __shared__ uint2 lc[LCAP];
    __shared__ unsigned lhp[HIST_SIZE / 2];
    __shared__ unsigned lcnt, gbase;
    if (threadIdx.x == 0) lcnt = 0u;
    for (int i = threadIdx.x; i < HIST_SIZE / 2; i += blockDim.x) lhp[i] = 0u;
    __syncthreads();
    const unsigned F = meta[4];
    unsigned* gcnt = &meta[0];
    unsigned* gh = ws + H_OFF + (blockIdx.x & (HREP - 1)) * HIST_SIZE;
    int stride = gridDim.x * blockDim.x;
    for (int i = blockIdx.x * blockDim.x + threadIdx.x; i < NV; i += stride) {
        float4 v = x[i];
        unsigned base = (unsigned)i * 4u;
        #pragma unroll
        for (int c = 0; c < 4; ++c) {
            float a = (c == 0) ? v.x : (c == 1) ? v.y : (c == 2) ? v.z : v.w;
            unsigned b = __float_as_uint(fmaxf(a, 0.f));
            if (b >= 1u && b < F) push_cand(b, base + (unsigned)c, &lcnt, lc, gcnt, cand, cap, gh);
        }
    }
    __syncthreads();
    unsigned n = lcnt < LCAP ? lcnt : LCAP;
    for (unsigned e = threadIdx.x; e < n; e += blockDim.x) {
        unsigned b12 = lc[e].x >> 20;
        atomicAdd(&lhp[b12 >> 1], 1u << ((b12 & 1u) * 16u));
    }
    __syncthreads();
    if (threadIdx.x == 0 && n) gbase = atomicAdd(gcnt, n);
    __syncthreads();
    for (unsigned e = threadIdx.x; e < n; e += blockDim.x) {
        unsigned q = gbase + e;
        if (q < cap) cand[q] = lc[e];
    }
    for (int i = threadIdx.x; i < HIST_SIZE / 2; i += blockDim.x) {
        unsigned w = lhp[i];
        if (w & 0xFFFFu) atomicAdd(&gh[i * 2],     w & 0xFFFFu);
        if (w >> 16)     atomicAdd(&gh[i * 2 + 1], w >> 16);
    }
}

// K5/K6 (1 block x 1024): suffix-scan replica-summed hist -> b12, c_above |
// fail | keepall.
__global__ void k_scan(unsigned* __restrict__ ws, const int* __restrict__ kptr, int is_fb) {
    unsigned* meta = ws + META_OFF;
    if (is_fb && meta[3] == 0u) return;
    __shared__ unsigned h[HIST_SIZE];
    __shared__ unsigned ps[1024];
    int t = threadIdx.x;
    unsigned nk = (unsigned)(*kptr) * 1024u;
    for (int i = t; i < HIST_SIZE; i += 1024) {
        unsigned s = 0u;
        #pragma unroll
        for (int r = 0; r < HREP; ++r) s += ws[H_OFF + r * HIST_SIZE + i];
        h[i] = s;
    }
    __syncthreads();
    unsigned p = h[t*4] + h[t*4+1] + h[t*4+2] + h[t*4+3];
    ps[t] = p;
    __syncthreads();
    for (int st = 1; st < 1024; st <<= 1) {
        unsigned v = (t + st < 1024) ? ps[t + st] : 0u;
        __syncthreads();
        ps[t] += v;
        __syncthreads();
    }
    unsigned total = ps[0];
    if (total < nk) {
        if (t == 0) {
            if (!is_fb) { meta[3] = 1u; meta[8] = meta[0]; }   // snapshot count
            else meta[5] = 1u;                                  // keep all positives
        }
        return;
    }
    unsigned S = (t < 1023) ? ps[t + 1] : 0u;
    for (int j = 3; j >= 0; --j) {
        int b = t * 4 + j;
        unsigned Sb = S + h[b];
        if (Sb >= nk && S < nk) { meta[1] = (unsigned)b; meta[2] = S; }
        S = Sb;
    }
}

// K7 (256 blocks): scatter definite keepers (bucket > b12) to out; compact
// cutoff-bucket cands -> cand2 + level-2 hist replicas. keepall: scatter all.
__global__ void k_filter(unsigned* __restrict__ ws, const uint2* __restrict__ cand,
                         uint2* __restrict__ cand2, float* __restrict__ out, unsigned cap) {
    unsigned* meta = ws + META_OFF;
    unsigned keepall = meta[5];
    unsigned ncand = meta[0]; if (ncand > cap) ncand = cap;
    unsigned stride = gridDim.x * blockDim.x;
    if (keepall) {
        for (unsigned i = blockIdx.x * blockDim.x + threadIdx.x; i < ncand; i += stride) {
            uint2 c = cand[i];
            out[c.y] = __uint_as_float(c.x);
        }
        return;
    }
    __shared__ uint2 lc[LCAP2];
    __shared__ unsigned lcnt, gbase;
    if (threadIdx.x == 0) lcnt = 0u;
    __syncthreads();
    unsigned b12 = meta[1];
    unsigned* h2 = ws + H2_OFF + (blockIdx.x & (HREP - 1)) * HIST_SIZE;
    unsigned* cnt2 = &meta[7];
    for (unsigned i = blockIdx.x * blockDim.x + threadIdx.x; i < ncand; i += stride) {
        uint2 c = cand[i];
        unsigned bk = c.x >> 20;
        if (bk > b12) {
            out[c.y] = __uint_as_float(c.x);       // definite keeper
        } else if (bk == b12) {
            atomicAdd(&h2[(c.x >> 8) & 0xFFFu], 1u);
            unsigned p = atomicAdd(&lcnt, 1u);
            if (p < LCAP2) lc[p] = c;
            else { unsigned q = atomicAdd(cnt2, 1u); if (q < CAND2_CAP) cand2[q] = c; }
        }
    }
    __syncthreads();
    unsigned n = lcnt < LCAP2 ? lcnt : LCAP2;
    if (threadIdx.x == 0 && n) gbase = atomicAdd(cnt2, n);
    __syncthreads();
    for (unsigned e = threadIdx.x; e < n; e += blockDim.x) {
        unsigned q = gbase + e;
        if (q < CAND2_CAP) cand2[q] = lc[e];
    }
}

// K8 (1 block x 1024): level-2/3 refinement -> exact tau; scatter in-bucket
// keepers (bits > tau) and the r lowest-index exact ties.
__global__ void k_select(unsigned* __restrict__ ws, const uint2* __restrict__ cand2,
                         float* __restrict__ out, const int* __restrict__ kptr) {
    unsigned* meta = ws + META_OFF;
    if (meta[5]) return;
    __shared__ unsigned h[HIST_SIZE];
    __shared__ unsigned ps[1024];
    __shared__ unsigned h3[256];
    __shared__ int ties[TIE_CAP];
    __shared__ unsigned tie_cnt;
    __shared__ unsigned s2_sh, ca2_sh, t3_sh, ca3_sh;
    int t = threadIdx.x;
    unsigned nk = (unsigned)(*kptr) * 1024u;
    unsigned b12 = meta[1];
    unsigned m = nk - meta[2];                     // rank within bucket b12, >=1
    unsigned n2 = meta[7]; if (n2 > CAND2_CAP) n2 = CAND2_CAP;
    for (int i = t; i < HIST_SIZE; i += 1024) {
        unsigned s = 0u;
        #pragma unroll
        for (int r = 0; r < HREP; ++r) s += ws[H2_OFF + r * HIST_SIZE + i];
        h[i] = s;
    }
    if (t < 256) h3[t] = 0u;
    if (t == 0) tie_cnt = 0u;
    __syncthreads();
    unsigned p = h[t*4] + h[t*4+1] + h[t*4+2] + h[t*4+3];
    ps[t] = p;
    __syncthreads();
    for (int st = 1; st < 1024; st <<= 1) {
        unsigned v = (t + st < 1024) ? ps[t + st] : 0u;
        __syncthreads();
        ps[t] += v;
        __syncthreads();
    }
    {
        unsigned S = (t < 1023) ? ps[t + 1] : 0u;
        for (int j = 3; j >= 0; --j) {
            int b = t * 4 + j;
            unsigned Sb = S + h[b];
            if (Sb >= m && S < m) { s2_sh = (unsigned)b; ca2_sh = S; }
            S = Sb;
        }
    }
    __syncthreads();
    unsigned s2 = s2_sh;
    unsigned m2 = m - ca2_sh;                      // rank within sub-bucket, >=1
    for (unsigned i = t; i < n2; i += 1024) {
        uint2 c = cand2[i];
        if (((c.x >> 8) & 0xFFFu) == s2) atomicAdd(&h3[c.x & 0xFFu], 1u);
    }
    __syncthreads();
    if (t < 256) ps[t] = h3[t];
    __syncthreads();
    for (int st = 1; st < 256; st <<= 1) {
        unsigned v = 0u;
        if (t < 256) v = (t + st < 256) ? ps[t + st] : 0u;
        __syncthreads();
        if (t < 256) ps[t] += v;
        __syncthreads();
    }
    if (t < 256) {
        unsigned S3 = (t < 255) ? ps[t + 1] : 0u;
        unsigned Sb = S3 + h3[t];
        if (Sb >= m2 && S3 < m2) { t3_sh = (unsigned)t; ca3_sh = S3; }
    }
    __syncthreads();
    unsigned tau = (b12 << 20) | (s2 << 8) | t3_sh;
    unsigned r = m2 - ca3_sh;                      // exact-tie keepers
    for (unsigned i = t; i < n2; i += 1024) {
        uint2 c = cand2[i];
        if (c.x > tau) {
            out[c.y] = __uint_as_float(c.x);       // in-bucket definite keeper
        } else if (c.x == tau) {
            unsigned q = atomicAdd(&tie_cnt, 1u);
            if (q < TIE_CAP) ties[q] = (int)c.y;
        }
    }
    __syncthreads();
    unsigned tc = tie_cnt; if (tc > TIE_CAP) tc = TIE_CAP;
    float tv = __uint_as_float(tau);
    for (unsigned e = t; e < tc; e += 1024) {
        int my = ties[e];
        unsigned rank = 0u;
        for (unsigned j = 0; j < tc; ++j) rank += (ties[j] < my) ? 1u : 0u;
        if (rank < r) out[my] = tv;                // keep r lowest-index ties
    }
}

extern "C" void kernel_launch(void* const* d_in, const int* in_sizes, int n_in,
                              void* d_out, int out_size, void* d_ws, size_t ws_size,
                              hipStream_t stream) {
    const float4* x = (const float4*)d_in[0];
    const int* kptr = (const int*)d_in[1];
    float* out = (float*)d_out;
    unsigned* ws32 = (unsigned*)d_ws;
    uint2* cand2 = (uint2*)(ws32 + CAND2_OFF);
    uint2* cand  = (uint2*)(ws32 + CAND_OFF);

    unsigned cap = CAND_CAP;
    size_t hdr = (size_t)CAND_OFF * 4;
    if (ws_size < hdr + (size_t)CAND_CAP * 8) {
        cap = (ws_size > hdr) ? (unsigned)((ws_size - hdr) / 8) : 0u;
    }

    hipMemsetAsync(d_out, 0, (size_t)out_size * sizeof(float), stream);  // 7TB/s fill
    k_prep<<<SREP, 256, 0, stream>>>(x, ws32);
    k_pick<<<1, 1024, 0, stream>>>(ws32, kptr);
    k_read<<<2048, 256, 0, stream>>>(x, ws32, cand, cap);
    k_scan<<<1, 1024, 0, stream>>>(ws32, kptr, 0);
    k_fb<<<2048, 256, 0, stream>>>(x, ws32, cand, cap);     // no-op unless fail
    k_scan<<<1, 1024, 0, stream>>>(ws32, kptr, 1);          // no-op unless fail
    k_filter<<<256, 256, 0, stream>>>(ws32, cand, cand2, out, cap);
    k_select<<<1, 1024, 0, stream>>>(ws32, cand2, out, kptr);
}

// Round 13
// 113.699 us; speedup vs baseline: 3.2646x; 1.2444x over previous
//
#include <hip/hip_runtime.h>

// BatchTopK: relu(x), keep global top (k*1024) of 1024*24576 fp32, zero rest.
// Exact radix-select on positive-fp32 bit patterns + index-ordered tie-break.
//
// R13: fused k_main (R5's fastest-measured hot loop, 63-66us) + slim tail.
// R12 proved the ~2TB/s write wall is context-imposed (vendor memset of out
// also ran at 1.7TB/s in-graph vs 6.9TB/s outside), so the fused main at
// 150MB/2.25TB/s ~ 67us IS the wall; optimization budget goes to the tail:
// 1/256 sample, fb self-guarded on meta[0] (pre-scan dropped), HREP=4,
// 7 launches, no fences, no memset.

#define N_ELEM   25165824            // 1024 * 24576
#define NV       (N_ELEM / 4)        // float4 count = 6291456 = 2048*256*12
#define HIST_SIZE 4096               // top-12-bit buckets
#define HREP     4                   // hist replicas
#define SREP     8                   // sample blocks / private replicas
#define NS       (NV / 256)          // sampled float4 count (1/256) = 24576
#define LCAP     1024                // per-block LDS candidate buffer
#define LCAP2    1024
#define TIE_CAP  4096
#define CAND2_CAP 262144
#define CAND_CAP  8388608

typedef float f32x4 __attribute__((ext_vector_type(4)));

// ws layout (uint32 words):
#define H_OFF     0                            // 4 x 4096 main hist (bits >= F)
#define H2_OFF    (H_OFF + HREP * HIST_SIZE)   // 16384: 4 x 4096 level-2 hist
#define HS_OFF    (H2_OFF + HREP * HIST_SIZE)  // 32768: 8 x 4096 sample replicas
#define META_OFF  (HS_OFF + SREP * HIST_SIZE)  // 65536: 32 words
#define CAND2_OFF (META_OFF + 32)              // 65568 (even -> uint2 ok)
#define CAND_OFF  (CAND2_OFF + 2 * CAND2_CAP)  // 589856 (even)
// meta: [0]=cand cnt [1]=b12 [2]=c_above [4]=F [5]=keepall [7]=cand2 cnt

// K1 (8 blocks): zero H+H2+meta; 1/256 sample -> private replica.
__global__ void k_prep(const float4* __restrict__ x, unsigned* __restrict__ ws) {
    __shared__ unsigned lh[HIST_SIZE];
    for (int i = threadIdx.x; i < HIST_SIZE; i += 256) lh[i] = 0u;
    int gid = blockIdx.x * 256 + threadIdx.x;
    for (int i = gid; i < HS_OFF; i += SREP * 256) ws[i] = 0u;   // zero H + H2
    if (gid < 32) ws[META_OFF + gid] = 0u;
    __syncthreads();
    for (int s = gid; s < NS; s += SREP * 256) {
        int c = s >> 6, l = s & 63;          // 64 consecutive f4 per 16384-f4 chunk
        float4 v = x[c * 16384 + l];
        if (v.x > 0.0f) atomicAdd(&lh[__float_as_uint(v.x) >> 20], 1u);
        if (v.y > 0.0f) atomicAdd(&lh[__float_as_uint(v.y) >> 20], 1u);
        if (v.z > 0.0f) atomicAdd(&lh[__float_as_uint(v.z) >> 20], 1u);
        if (v.w > 0.0f) atomicAdd(&lh[__float_as_uint(v.w) >> 20], 1u);
    }
    __syncthreads();
    unsigned* hs = ws + HS_OFF + blockIdx.x * HIST_SIZE;
    for (int i = threadIdx.x; i < HIST_SIZE; i += 256) hs[i] = lh[i];
}

// K2 (1 block x 1024): F = highest bucket with sampled suffix >= nk/128
// (1/256 sample -> E[count_full(>=F)] ~ 2*nk; k_fb guards exactness).
__global__ void k_pick(unsigned* __restrict__ ws, const int* __restrict__ kptr) {
    __shared__ unsigned h[HIST_SIZE];
    __shared__ unsigned ps[1024];
    __shared__ unsigned F_sh;
    int t = threadIdx.x;
    if (t == 0) F_sh = 1u;
    unsigned nk = (unsigned)(*kptr) * 1024u;
    unsigned thr = nk / 128u; if (thr < 1u) thr = 1u;
    for (int i = t; i < HIST_SIZE; i += 1024) {
        unsigned s = 0u;
        #pragma unroll
        for (int r = 0; r < SREP; ++r) s += ws[HS_OFF + r * HIST_SIZE + i];
        h[i] = s;
    }
    __syncthreads();
    unsigned p = h[t*4] + h[t*4+1] + h[t*4+2] + h[t*4+3];
    ps[t] = p;
    __syncthreads();
    for (int st = 1; st < 1024; st <<= 1) {
        unsigned v = (t + st < 1024) ? ps[t + st] : 0u;
        __syncthreads();
        ps[t] += v;
        __syncthreads();
    }
    unsigned S = (t < 1023) ? ps[t + 1] : 0u;
    for (int j = 3; j >= 0; --j) {
        int b = t * 4 + j;
        unsigned Sb = S + h[b];
        if (Sb >= thr && S < thr) F_sh = ((unsigned)b) << 20;
        S = Sb;
    }
    __syncthreads();
    if (t == 0) ws[META_OFF + 4] = F_sh;
}

__device__ __forceinline__ void cand_push(unsigned b, unsigned idx,
                                          unsigned* lcnt, uint2* lc,
                                          unsigned* gcnt, uint2* cand, unsigned cap,
                                          unsigned* gh) {
    unsigned p = atomicAdd(lcnt, 1u);
    if (p < LCAP) lc[p] = make_uint2(b, idx);
    else {                                    // spill (~never): keep hist exact
        unsigned q = atomicAdd(gcnt, 1u);
        if (q < cap) { cand[q] = make_uint2(b, idx); atomicAdd(&gh[b >> 20], 1u); }
    }
}

// K3 (2048 x 256): fused single pass (R5 hot-loop shape, fastest measured):
// 4-wide groups of {load f4, NT-store zero, compact >= F}. Epilogue:
// block-local packed-u16 candidate histogram + single global-atomic flush.
__global__ __launch_bounds__(256) void k_main(const float4* __restrict__ x,
                                              float4* __restrict__ out,
                                              unsigned* __restrict__ ws,
                                              uint2* __restrict__ cand, unsigned cap) {
    __shared__ uint2 lc[LCAP];               // 8 KB
    __shared__ unsigned lhp[HIST_SIZE / 2];  // 8 KB packed u16 pairs
    __shared__ unsigned lcnt, gbase;
    if (threadIdx.x == 0) lcnt = 0u;
    for (int i = threadIdx.x; i < HIST_SIZE / 2; i += 256) lhp[i] = 0u;
    __syncthreads();
    unsigned* meta = ws + META_OFF;
    const unsigned F = meta[4];
    unsigned* gcnt = &meta[0];
    unsigned* gh = ws + H_OFF + (blockIdx.x & (HREP - 1)) * HIST_SIZE;
    const f32x4 z = {0.f, 0.f, 0.f, 0.f};
    int tid = blockIdx.x * 256 + threadIdx.x;
    const int stride = 2048 * 256;
    #pragma unroll
    for (int j = 0; j < 12; j += 4) {
        int i0 = tid + (j + 0) * stride;
        int i1 = tid + (j + 1) * stride;
        int i2 = tid + (j + 2) * stride;
        int i3 = tid + (j + 3) * stride;
        float4 v0 = x[i0];
        float4 v1 = x[i1];
        float4 v2 = x[i2];
        float4 v3 = x[i3];
        __builtin_nontemporal_store(z, (f32x4*)&out[i0]);
        __builtin_nontemporal_store(z, (f32x4*)&out[i1]);
        __builtin_nontemporal_store(z, (f32x4*)&out[i2]);
        __builtin_nontemporal_store(z, (f32x4*)&out[i3]);
        #pragma unroll
        for (int q = 0; q < 4; ++q) {
            float4 v = (q == 0) ? v0 : (q == 1) ? v1 : (q == 2) ? v2 : v3;
            int ii = (q == 0) ? i0 : (q == 1) ? i1 : (q == 2) ? i2 : i3;
            unsigned base = (unsigned)ii * 4u;
            unsigned b;
            b = __float_as_uint(fmaxf(v.x, 0.f)); if (b >= F) cand_push(b, base + 0u, &lcnt, lc, gcnt, cand, cap, gh);
            b = __float_as_uint(fmaxf(v.y, 0.f)); if (b >= F) cand_push(b, base + 1u, &lcnt, lc, gcnt, cand, cap, gh);
            b = __float_as_uint(fmaxf(v.z, 0.f)); if (b >= F) cand_push(b, base + 2u, &lcnt, lc, gcnt, cand, cap, gh);
            b = __float_as_uint(fmaxf(v.w, 0.f)); if (b >= F) cand_push(b, base + 3u, &lcnt, lc, gcnt, cand, cap, gh);
        }
    }
    __syncthreads();
    unsigned n = lcnt < LCAP ? lcnt : LCAP;
    for (unsigned e = threadIdx.x; e < n; e += 256) {
        unsigned b12 = lc[e].x >> 20;
        atomicAdd(&lhp[b12 >> 1], 1u << ((b12 & 1u) * 16u));
    }
    __syncthreads();
    if (threadIdx.x == 0 && n) gbase = atomicAdd(gcnt, n);
    __syncthreads();
    for (unsigned e = threadIdx.x; e < n; e += 256) {
        unsigned q = gbase + e;
        if (q < cap) cand[q] = lc[e];
    }
    for (int i = threadIdx.x; i < HIST_SIZE / 2; i += 256) {
        unsigned w = lhp[i];
        if (w & 0xFFFFu) atomicAdd(&gh[i * 2],     w & 0xFFFFu);
        if (w >> 16)     atomicAdd(&gh[i * 2 + 1], w >> 16);
    }
}

// K4 (2048, self-guarded): meta[0] == exact count(bits>=F). If >= nk, floor
// was safe -> return. Else complement pass (0 < bits < F) appends candidates
// + hist counts, restoring full-histogram exactness.
__global__ void k_fb(const float4* __restrict__ x, unsigned* __restrict__ ws,
                     uint2* __restrict__ cand, unsigned cap,
                     const int* __restrict__ kptr) {
    unsigned* meta = ws + META_OFF;
    unsigned nk = (unsigned)(*kptr) * 1024u;
    if (meta[0] >= nk) return;               // floor held (normal path)
    __shared__ uint2 lc[LCAP];
    __shared__ unsigned lhp[HIST_SIZE / 2];
    __shared__ unsigned lcnt, gbase;
    if (threadIdx.x == 0) lcnt = 0u;
    for (int i = threadIdx.x; i < HIST_SIZE / 2; i += blockDim.x) lhp[i] = 0u;
    __syncthreads();
    const unsigned F = meta[4];
    unsigned* gcnt = &meta[0];
    unsigned* gh = ws + H_OFF + (blockIdx.x & (HREP - 1)) * HIST_SIZE;
    int stride = gridDim.x * blockDim.x;
    for (int i = blockIdx.x * blockDim.x + threadIdx.x; i < NV; i += stride) {
        float4 v = x[i];
        unsigned base = (unsigned)i * 4u;
        #pragma unroll
        for (int c = 0; c < 4; ++c) {
            float a = (c == 0) ? v.x : (c == 1) ? v.y : (c == 2) ? v.z : v.w;
            unsigned b = __float_as_uint(fmaxf(a, 0.f));
            if (b >= 1u && b < F) cand_push(b, base + (unsigned)c, &lcnt, lc, gcnt, cand, cap, gh);
        }
    }
    __syncthreads();
    unsigned n = lcnt < LCAP ? lcnt : LCAP;
    for (unsigned e = threadIdx.x; e < n; e += blockDim.x) {
        unsigned b12 = lc[e].x >> 20;
        atomicAdd(&lhp[b12 >> 1], 1u << ((b12 & 1u) * 16u));
    }
    __syncthreads();
    if (threadIdx.x == 0 && n) gbase = atomicAdd(gcnt, n);
    __syncthreads();
    for (unsigned e = threadIdx.x; e < n; e += blockDim.x) {
        unsigned q = gbase + e;
        if (q < cap) cand[q] = lc[e];
    }
    for (int i = threadIdx.x; i < HIST_SIZE / 2; i += blockDim.x) {
        unsigned w = lhp[i];
        if (w & 0xFFFFu) atomicAdd(&gh[i * 2],     w & 0xFFFFu);
        if (w >> 16)     atomicAdd(&gh[i * 2 + 1], w >> 16);
    }
}

// K5 (1 block x 1024): suffix-scan replica-summed hist -> b12, c_above,
// or keepall if fewer than nk positives total.
__global__ void k_scan(unsigned* __restrict__ ws, const int* __restrict__ kptr) {
    unsigned* meta = ws + META_OFF;
    __shared__ unsigned h[HIST_SIZE];
    __shared__ unsigned ps[1024];
    int t = threadIdx.x;
    unsigned nk = (unsigned)(*kptr) * 1024u;
    for (int i = t; i < HIST_SIZE; i += 1024) {
        unsigned s = 0u;
        #pragma unroll
        for (int r = 0; r < HREP; ++r) s += ws[H_OFF + r * HIST_SIZE + i];
        h[i] = s;
    }
    __syncthreads();
    unsigned p = h[t*4] + h[t*4+1] + h[t*4+2] + h[t*4+3];
    ps[t] = p;
    __syncthreads();
    for (int st = 1; st < 1024; st <<= 1) {
        unsigned v = (t + st < 1024) ? ps[t + st] : 0u;
        __syncthreads();
        ps[t] += v;
        __syncthreads();
    }
    unsigned total = ps[0];
    if (total < nk) {
        if (t == 0) meta[5] = 1u;            // keep all positives
        return;
    }
    unsigned S = (t < 1023) ? ps[t + 1] : 0u;
    for (int j = 3; j >= 0; --j) {
        int b = t * 4 + j;
        unsigned Sb = S + h[b];
        if (Sb >= nk && S < nk) { meta[1] = (unsigned)b; meta[2] = S; }
        S = Sb;
    }
}

// K6 (256 blocks): scatter definite keepers (bucket > b12) to out; compact
// cutoff-bucket cands -> cand2 + level-2 hist replicas. keepall: scatter all.
__global__ void k_filter(unsigned* __restrict__ ws, const uint2* __restrict__ cand,
                         uint2* __restrict__ cand2, float* __restrict__ out, unsigned cap) {
    unsigned* meta = ws + META_OFF;
    unsigned keepall = meta[5];
    unsigned ncand = meta[0]; if (ncand > cap) ncand = cap;
    unsigned stride = gridDim.x * blockDim.x;
    if (keepall) {
        for (unsigned i = blockIdx.x * blockDim.x + threadIdx.x; i < ncand; i += stride) {
            uint2 c = cand[i];
            out[c.y] = __uint_as_float(c.x);
        }
        return;
    }
    __shared__ uint2 lc[LCAP2];
    __shared__ unsigned lcnt, gbase;
    if (threadIdx.x == 0) lcnt = 0u;
    __syncthreads();
    unsigned b12 = meta[1];
    unsigned* h2 = ws + H2_OFF + (blockIdx.x & (HREP - 1)) * HIST_SIZE;
    unsigned* cnt2 = &meta[7];
    for (unsigned i = blockIdx.x * blockDim.x + threadIdx.x; i < ncand; i += stride) {
        uint2 c = cand[i];
        unsigned bk = c.x >> 20;
        if (bk > b12) {
            out[c.y] = __uint_as_float(c.x);       // definite keeper
        } else if (bk == b12) {
            atomicAdd(&h2[(c.x >> 8) & 0xFFFu], 1u);
            unsigned p = atomicAdd(&lcnt, 1u);
            if (p < LCAP2) lc[p] = c;
            else { unsigned q = atomicAdd(cnt2, 1u); if (q < CAND2_CAP) cand2[q] = c; }
        }
    }
    __syncthreads();
    unsigned n = lcnt < LCAP2 ? lcnt : LCAP2;
    if (threadIdx.x == 0 && n) gbase = atomicAdd(cnt2, n);
    __syncthreads();
    for (unsigned e = threadIdx.x; e < n; e += blockDim.x) {
        unsigned q = gbase + e;
        if (q < CAND2_CAP) cand2[q] = lc[e];
    }
}

// K7 (1 block x 1024): level-2/3 refinement -> exact tau; scatter in-bucket
// keepers (bits > tau) and the r lowest-index exact ties.
__global__ void k_select(unsigned* __restrict__ ws, const uint2* __restrict__ cand2,
                         float* __restrict__ out, const int* __restrict__ kptr) {
    unsigned* meta = ws + META_OFF;
    if (meta[5]) return;
    __shared__ unsigned h[HIST_SIZE];
    __shared__ unsigned ps[1024];
    __shared__ unsigned h3[256];
    __shared__ int ties[TIE_CAP];
    __shared__ unsigned tie_cnt;
    __shared__ unsigned s2_sh, ca2_sh, t3_sh, ca3_sh;
    int t = threadIdx.x;
    unsigned nk = (unsigned)(*kptr) * 1024u;
    unsigned b12 = meta[1];
    unsigned m = nk - meta[2];                     // rank within bucket b12, >=1
    unsigned n2 = meta[7]; if (n2 > CAND2_CAP) n2 = CAND2_CAP;
    for (int i = t; i < HIST_SIZE; i += 1024) {
        unsigned s = 0u;
        #pragma unroll
        for (int r = 0; r < HREP; ++r) s += ws[H2_OFF + r * HIST_SIZE + i];
        h[i] = s;
    }
    if (t < 256) h3[t] = 0u;
    if (t == 0) tie_cnt = 0u;
    __syncthreads();
    unsigned p = h[t*4] + h[t*4+1] + h[t*4+2] + h[t*4+3];
    ps[t] = p;
    __syncthreads();
    for (int st = 1; st < 1024; st <<= 1) {
        unsigned v = (t + st < 1024) ? ps[t + st] : 0u;
        __syncthreads();
        ps[t] += v;
        __syncthreads();
    }
    {
        unsigned S = (t < 1023) ? ps[t + 1] : 0u;
        for (int j = 3; j >= 0; --j) {
            int b = t * 4 + j;
            unsigned Sb = S + h[b];
            if (Sb >= m && S < m) { s2_sh = (unsigned)b; ca2_sh = S; }
            S = Sb;
        }
    }
    __syncthreads();
    unsigned s2 = s2_sh;
    unsigned m2 = m - ca2_sh;                      // rank within sub-bucket, >=1
    for (unsigned i = t; i < n2; i += 1024) {
        uint2 c = cand2[i];
        if (((c.x >> 8) & 0xFFFu) == s2) atomicAdd(&h3[c.x & 0xFFu], 1u);
    }
    __syncthreads();
    if (t < 256) ps[t] = h3[t];
    __syncthreads();
    for (int st = 1; st < 256; st <<= 1) {
        unsigned v = 0u;
        if (t < 256) v = (t + st < 256) ? ps[t + st] : 0u;
        __syncthreads();
        if (t < 256) ps[t] += v;
        __syncthreads();
    }
    if (t < 256) {
        unsigned S3 = (t < 255) ? ps[t + 1] : 0u;
        unsigned Sb = S3 + h3[t];
        if (Sb >= m2 && S3 < m2) { t3_sh = (unsigned)t; ca3_sh = S3; }
    }
    __syncthreads();
    unsigned tau = (b12 << 20) | (s2 << 8) | t3_sh;
    unsigned r = m2 - ca3_sh;                      // exact-tie keepers
    for (unsigned i = t; i < n2; i += 1024) {
        uint2 c = cand2[i];
        if (c.x > tau) {
            out[c.y] = __uint_as_float(c.x);       // in-bucket definite keeper
        } else if (c.x == tau) {
            unsigned q = atomicAdd(&tie_cnt, 1u);
            if (q < TIE_CAP) ties[q] = (int)c.y;
        }
    }
    __syncthreads();
    unsigned tc = tie_cnt; if (tc > TIE_CAP) tc = TIE_CAP;
    float tv = __uint_as_float(tau);
    for (unsigned e = t; e < tc; e += 1024) {
        int my = ties[e];
        unsigned rank = 0u;
        for (unsigned j = 0; j < tc; ++j) rank += (ties[j] < my) ? 1u : 0u;
        if (rank < r) out[my] = tv;                // keep r lowest-index ties
    }
}

extern "C" void kernel_launch(void* const* d_in, const int* in_sizes, int n_in,
                              void* d_out, int out_size, void* d_ws, size_t ws_size,
                              hipStream_t stream) {
    const float4* x = (const float4*)d_in[0];
    const int* kptr = (const int*)d_in[1];
    float* out = (float*)d_out;
    unsigned* ws32 = (unsigned*)d_ws;
    uint2* cand2 = (uint2*)(ws32 + CAND2_OFF);
    uint2* cand  = (uint2*)(ws32 + CAND_OFF);

    unsigned cap = CAND_CAP;
    size_t hdr = (size_t)CAND_OFF * 4;
    if (ws_size < hdr + (size_t)CAND_CAP * 8) {
        cap = (ws_size > hdr) ? (unsigned)((ws_size - hdr) / 8) : 0u;
    }

    k_prep<<<SREP, 256, 0, stream>>>(x, ws32);
    k_pick<<<1, 1024, 0, stream>>>(ws32, kptr);
    k_main<<<2048, 256, 0, stream>>>(x, (float4*)out, ws32, cand, cap);
    k_fb<<<2048, 256, 0, stream>>>(x, ws32, cand, cap, kptr);   // self-guarded no-op
    k_scan<<<1, 1024, 0, stream>>>(ws32, kptr);
    k_filter<<<256, 256, 0, stream>>>(ws32, cand, cand2, out, cap);
    k_select<<<1, 1024, 0, stream>>>(ws32, cand2, out, kptr);
}